// Round 9
// baseline (706.584 us; speedup 1.0000x reference)
//
#include <hip/hip_runtime.h>
#include <hip/hip_bf16.h>
#include <stdint.h>

// Problem dims (fixed by setup_inputs)
#define T_DIM 2048
#define I_DIM 4096
#define O_DIM 4096
#define R_DIM 16
#define QBLK  32

typedef __bf16 bf16x8 __attribute__((ext_vector_type(8)));
typedef float  floatx4 __attribute__((ext_vector_type(4)));
typedef unsigned short ushort_t;

#define AS1 __attribute__((address_space(1)))
#define AS3 __attribute__((address_space(3)))

__device__ __forceinline__ ushort_t f2bf(float f) {
  unsigned u = __float_as_uint(f);
  u += 0x7FFFu + ((u >> 16) & 1u);   // round-to-nearest-even
  return (ushort_t)(u >> 16);
}

__device__ __forceinline__ float dot4(float4 a, float4 b) {
  return a.x * b.x + a.y * b.y + a.z * b.z + a.w * b.w;
}

// ---------------- k_stream (R13): xb=bf16(x) | wb=dequant(q) -----------
__global__ __launch_bounds__(256) void k_stream(const float* __restrict__ x,
                                                const int* __restrict__ q,
                                                const float* __restrict__ scales,
                                                ushort_t* __restrict__ xb,
                                                ushort_t* __restrict__ wb) {
  const int b = blockIdx.x, tid = threadIdx.x;
  if (b < 512) {                              // ---- prep_x
    const int stride = 512 * 256;
    const int u0 = b * 256 + tid;
    float4 v[4][4];
#pragma unroll
    for (int j = 0; j < 4; ++j) {
      const float4* p = (const float4*)x + (size_t)(u0 + j * stride) * 4;
      v[j][0] = p[0]; v[j][1] = p[1]; v[j][2] = p[2]; v[j][3] = p[3];
    }
#pragma unroll
    for (int j = 0; j < 4; ++j) {
      const size_t u = u0 + (size_t)j * stride;
      union { ushort_t us[16]; uint4 o[2]; } r;
#pragma unroll
      for (int k = 0; k < 4; ++k) {
        r.us[k * 4 + 0] = f2bf(v[j][k].x); r.us[k * 4 + 1] = f2bf(v[j][k].y);
        r.us[k * 4 + 2] = f2bf(v[j][k].z); r.us[k * 4 + 3] = f2bf(v[j][k].w);
      }
      ((uint4*)xb)[u * 2] = r.o[0];
      ((uint4*)xb)[u * 2 + 1] = r.o[1];
    }
    return;
  }
  {                                           // ---- prep_w
    const int stride = 1024 * 256;
    const int u0 = (b - 512) * 256 + tid;
    int4 v[4][4];
    float s[4];
#pragma unroll
    for (int j = 0; j < 4; ++j) {
      const size_t u = u0 + (size_t)j * stride;
      const int4* p = (const int4*)q + u * 4;
      v[j][0] = p[0]; v[j][1] = p[1]; v[j][2] = p[2]; v[j][3] = p[3];
      const size_t e = u * 16;
      s[j] = scales[(e >> 12) * (I_DIM / QBLK) + ((e & 4095) >> 5)];
    }
#pragma unroll
    for (int j = 0; j < 4; ++j) {
      const size_t u = u0 + (size_t)j * stride;
      const float sj = s[j];
      union { ushort_t us[16]; uint4 o[2]; } r;
#pragma unroll
      for (int k = 0; k < 4; ++k) {
        r.us[k * 4 + 0] = f2bf((float)(v[j][k].x - 8) * sj);
        r.us[k * 4 + 1] = f2bf((float)(v[j][k].y - 8) * sj);
        r.us[k * 4 + 2] = f2bf((float)(v[j][k].z - 8) * sj);
        r.us[k * 4 + 3] = f2bf((float)(v[j][k].w - 8) * sj);
      }
      ((uint4*)wb)[u * 2] = r.o[0];
      ((uint4*)wb)[u * 2 + 1] = r.o[1];
    }
  }
}

// ---------------- k_xd: xd = alpha * (x @ down^T) ----------------------
__global__ __launch_bounds__(256) void k_xd(const float* __restrict__ x,
                                            const float* __restrict__ down,
                                            const float* __restrict__ alphap,
                                            float* __restrict__ xd) {
  __shared__ float ds[16 * 512];              // 32 KB
  const int b = blockIdx.x, tid = threadIdx.x;
  const int tl = tid >> 5, s = tid & 31;
  const int t = b * 8 + tl;
  float acc[16];
#pragma unroll
  for (int r = 0; r < 16; ++r) acc[r] = 0.f;
  for (int c = 0; c < 8; ++c) {
    const int ib = c * 512;
    __syncthreads();
#pragma unroll
    for (int j = 0; j < 8; ++j) {
      int e = j * 256 + tid;
      int r = e >> 7, col = e & 127;
      ((float4*)ds)[e] = ((const float4*)(down + (size_t)r * I_DIM + ib))[col];
    }
    __syncthreads();
#pragma unroll
    for (int j = 0; j < 4; ++j) {
      float4 xv = ((const float4*)(x + (size_t)t * I_DIM + ib))[s + 32 * j];
#pragma unroll
      for (int r = 0; r < 16; ++r) {
        float4 dv = ((const float4*)ds)[r * 128 + s + 32 * j];
        acc[r] += dot4(xv, dv);
      }
    }
  }
  const float al = alphap[0];
#pragma unroll
  for (int r = 0; r < 16; ++r) {
    float v = acc[r];
    v += __shfl_down(v, 16, 32);
    v += __shfl_down(v, 8, 32);
    v += __shfl_down(v, 4, 32);
    v += __shfl_down(v, 2, 32);
    v += __shfl_down(v, 1, 32);
    if (s == 0) xd[t * 16 + r] = v * al;
  }
}

// ======================= R14 main GEMM: m201 256-sq port ===============
// First faithful instance of the certified 256^2 8-wave template (guide
// S5: 1563 TF @4k). BM=BN=256, BK=64, 512 thr / 8 waves (2Mx4N),
// per-wave 128x64, acc[8][4] (128 AGPR, 1 block/CU). Grid 16x8 = 128
// blocks (0.5/CU accepted). Dbuf LDS 128KB. 4 phases per K-tile, each
// {ds_read subtile | stage 1 half-tile -> barrier -> lgkm(0) -> SB(0) ->
// setprio -> 16 MFMA -> setprio -> barrier}. Register-reuse ordering:
// A-M0 held ph0-1, B held ph0-3, A-M1 read ph2 -> A(kt+1) staged ph0-1
// (other slot), B(kt+2) staged ph2-3 (same slot, after B reads done).
// vmcnt(4) once per tile, never 0 until tail.

#define BK 64
#define NT (I_DIM / BK)          // 64 K-tiles
#define SLOT_E (256 * BK)        // 16384 elems = 32 KB per A/B slot
#define HALF_E (128 * BK)        // 8192 elems = 16 KB per half

__device__ __forceinline__ bf16x8 lds_read16(unsigned addr) {
  bf16x8 d;
  asm volatile("ds_read_b128 %0, %1" : "=v"(d) : "v"(addr));
  return d;
}

// Stage one 128x64 half-tile (16 KB): 1024 granules, 2 gload_lds/thread.
// LDS dest linear; global col-granule pre-swizzled with involution
// g -> g ^ (r&7) (r = local row; half base is 128-aligned so r&7 == glob).
__device__ __forceinline__ void stage_half(const ushort_t* __restrict__ g,
                                           ushort_t* dst, int tid) {
#pragma unroll
  for (int it = 0; it < 2; ++it) {
    const int seg = it * 512 + tid;
    const int r = seg >> 3, cg = (seg & 7) ^ (r & 7);
    __builtin_amdgcn_global_load_lds(
        (const AS1 char*)(g + (size_t)r * I_DIM + cg * 8),
        (AS3 char*)(dst + (size_t)seg * 8), 16, 0, 0);
  }
}

#define PHASE_SYNC()                                          \
  __builtin_amdgcn_s_barrier();                               \
  asm volatile("s_waitcnt lgkmcnt(0)" ::: "memory");          \
  __builtin_amdgcn_sched_barrier(0);                          \
  __builtin_amdgcn_s_setprio(1)

#define PHASE_END()                                           \
  __builtin_amdgcn_s_setprio(0);                              \
  __builtin_amdgcn_s_barrier()

// One K-tile: 4 phases. VM: vmcnt at tile end (4 steady / 0 / -1 none).
// SA: stage A(kt+1) -> Ast. SB_: stage B(kt+2) -> Bst.
template<int VM, bool SA, bool SB_>
__device__ __forceinline__ void ktile(unsigned aB, unsigned bB,
                                      ushort_t* Ast, ushort_t* Bst,
                                      const ushort_t* gA, const ushort_t* gB,
                                      floatx4 (&acc)[8][4],
                                      int wm, int wn, int quad, int m16, int tid) {
  bf16x8 a0[4], a1[4], b0k0[2], b0k1[2], b1k0[2], b1k1[2];

  // ---- phase 0: read A-M0 (k0,k1) + B-N0; MFMA quadrant (M0,N0) ----
#pragma unroll
  for (int i = 0; i < 4; ++i) {
    const int m = wm * 128 + i * 16 + m16;
    a0[i] = lds_read16(aB + (unsigned)((m * 8 + (quad ^ (m & 7))) * 16));
    a1[i] = lds_read16(aB + (unsigned)((m * 8 + ((4 + quad) ^ (m & 7))) * 16));
  }
#pragma unroll
  for (int j = 0; j < 2; ++j) {
    const int n = wn * 64 + j * 16 + m16;
    b0k0[j] = lds_read16(bB + (unsigned)((n * 8 + (quad ^ (n & 7))) * 16));
    b0k1[j] = lds_read16(bB + (unsigned)((n * 8 + ((4 + quad) ^ (n & 7))) * 16));
  }
  if constexpr (SA) stage_half(gA, Ast, tid);
  PHASE_SYNC();
#pragma unroll
  for (int i = 0; i < 4; ++i)
#pragma unroll
    for (int j = 0; j < 2; ++j) {
      acc[i][j] = __builtin_amdgcn_mfma_f32_16x16x32_bf16(a0[i], b0k0[j], acc[i][j], 0, 0, 0);
      acc[i][j] = __builtin_amdgcn_mfma_f32_16x16x32_bf16(a1[i], b0k1[j], acc[i][j], 0, 0, 0);
    }
  PHASE_END();

  // ---- phase 1: read B-N1; MFMA (M0,N1) with held A ----
#pragma unroll
  for (int j = 0; j < 2; ++j) {
    const int n = wn * 64 + (2 + j) * 16 + m16;
    b1k0[j] = lds_read16(bB + (unsigned)((n * 8 + (quad ^ (n & 7))) * 16));
    b1k1[j] = lds_read16(bB + (unsigned)((n * 8 + ((4 + quad) ^ (n & 7))) * 16));
  }
  if constexpr (SA) stage_half(gA + (size_t)128 * I_DIM, Ast + HALF_E, tid);
  PHASE_SYNC();
#pragma unroll
  for (int i = 0; i < 4; ++i)
#pragma unroll
    for (int j = 0; j < 2; ++j) {
      acc[i][2 + j] = __builtin_amdgcn_mfma_f32_16x16x32_bf16(a0[i], b1k0[j], acc[i][2 + j], 0, 0, 0);
      acc[i][2 + j] = __builtin_amdgcn_mfma_f32_16x16x32_bf16(a1[i], b1k1[j], acc[i][2 + j], 0, 0, 0);
    }
  PHASE_END();

  // ---- phase 2: read A-M1 (B slot region now dead -> stage B(kt+2)) ----
#pragma unroll
  for (int i = 0; i < 4; ++i) {
    const int m = wm * 128 + 64 + i * 16 + m16;
    a0[i] = lds_read16(aB + (unsigned)((m * 8 + (quad ^ (m & 7))) * 16));
    a1[i] = lds_read16(aB + (unsigned)((m * 8 + ((4 + quad) ^ (m & 7))) * 16));
  }
  if constexpr (SB_) stage_half(gB, Bst, tid);
  PHASE_SYNC();
#pragma unroll
  for (int i = 0; i < 4; ++i)
#pragma unroll
    for (int j = 0; j < 2; ++j) {
      acc[4 + i][j] = __builtin_amdgcn_mfma_f32_16x16x32_bf16(a0[i], b0k0[j], acc[4 + i][j], 0, 0, 0);
      acc[4 + i][j] = __builtin_amdgcn_mfma_f32_16x16x32_bf16(a1[i], b0k1[j], acc[4 + i][j], 0, 0, 0);
    }
  PHASE_END();

  // ---- phase 3: no reads; MFMA (M1,N1); tile-end counted vmcnt ----
  if constexpr (SB_) stage_half(gB + (size_t)128 * I_DIM, Bst + HALF_E, tid);
  __builtin_amdgcn_s_barrier();
  __builtin_amdgcn_s_setprio(1);
#pragma unroll
  for (int i = 0; i < 4; ++i)
#pragma unroll
    for (int j = 0; j < 2; ++j) {
      acc[4 + i][2 + j] = __builtin_amdgcn_mfma_f32_16x16x32_bf16(a0[i], b1k0[j], acc[4 + i][2 + j], 0, 0, 0);
      acc[4 + i][2 + j] = __builtin_amdgcn_mfma_f32_16x16x32_bf16(a1[i], b1k1[j], acc[4 + i][2 + j], 0, 0, 0);
    }
  __builtin_amdgcn_s_setprio(0);
  if constexpr (VM == 4)      asm volatile("s_waitcnt vmcnt(4)" ::: "memory");
  else if constexpr (VM == 0) asm volatile("s_waitcnt vmcnt(0)" ::: "memory");
  if constexpr (VM >= 0) __builtin_amdgcn_sched_barrier(0);
  __builtin_amdgcn_s_barrier();
}

__global__ __launch_bounds__(512, 2) void k_gemm(const ushort_t* __restrict__ xb,
                                                 const ushort_t* __restrict__ wb,
                                                 const float* __restrict__ bias,
                                                 const float* __restrict__ xd,
                                                 const float* __restrict__ up,
                                                 float* __restrict__ y) {
  __shared__ __align__(16) ushort_t As[2][SLOT_E];   // 64 KB
  __shared__ __align__(16) ushort_t Bs[2][SLOT_E];   // 64 KB

  const int tid = threadIdx.x;
  const int lane = tid & 63, wv = tid >> 6;
  const int quad = lane >> 4, m16 = lane & 15;
  const int wm = wv >> 2, wn = wv & 3;     // 2(M) x 4(N) waves

  const int oT = blockIdx.x * 256, tT = blockIdx.y * 256;
  const ushort_t* ap = xb + (size_t)tT * I_DIM;
  const ushort_t* bp = wb + (size_t)oT * I_DIM;

  const unsigned aL = (unsigned)(uintptr_t)(AS3 ushort_t*)&As[0][0];
  const unsigned bL = (unsigned)(uintptr_t)(AS3 ushort_t*)&Bs[0][0];
  const unsigned A0 = aL, A1 = aL + SLOT_E * 2;
  const unsigned B0 = bL, B1 = bL + SLOT_E * 2;

  floatx4 acc[8][4] = {};

  // Prologue: A(0)->slot0, B(0)->slot0, B(1)->slot1 (12 loads/thread);
  // vmcnt(4) -> tile0 ready, B(1) still in flight.
  stage_half(ap, &As[0][0], tid);
  stage_half(ap + (size_t)128 * I_DIM, &As[0][0] + HALF_E, tid);
  stage_half(bp, &Bs[0][0], tid);
  stage_half(bp + (size_t)128 * I_DIM, &Bs[0][0] + HALF_E, tid);
  stage_half(bp + BK, &Bs[1][0], tid);
  stage_half(bp + (size_t)128 * I_DIM + BK, &Bs[1][0] + HALF_E, tid);
  asm volatile("s_waitcnt vmcnt(4)" ::: "memory");
  __builtin_amdgcn_sched_barrier(0);
  __builtin_amdgcn_s_barrier();

  // Steady: during kt stage A(kt+1) -> other slot (ph0-1) and
  // B(kt+2) -> same slot (ph2-3). kt = 0..61 as 31 even/odd pairs.
  for (int g = 0; g < 31; ++g) {
    const int kt = 2 * g;
    ktile<4, true, true>(A0, B0, &As[1][0], &Bs[0][0],
                         ap + (size_t)(kt + 1) * BK, bp + (size_t)(kt + 2) * BK,
                         acc, wm, wn, quad, m16, tid);
    ktile<4, true, true>(A1, B1, &As[0][0], &Bs[1][0],
                         ap + (size_t)(kt + 2) * BK, bp + (size_t)(kt + 3) * BK,
                         acc, wm, wn, quad, m16, tid);
  }
  // kt=62: stage A(63) only; drain everything (vmcnt 0).
  ktile<0, true, false>(A0, B0, &As[1][0], nullptr,
                        ap + (size_t)63 * BK, nullptr,
                        acc, wm, wn, quad, m16, tid);
  // kt=63: pure compute.
  ktile<-1, false, false>(A1, B1, nullptr, nullptr, nullptr, nullptr,
                          acc, wm, wn, quad, m16, tid);

  // Epilogue: y[t][o] = acc + dot16(xd[t], up[o]) + bias[o]
  // C/D layout: row = quad*4+reg, col = lane&15 (m89-verified).
#pragma unroll
  for (int im = 0; im < 8; ++im) {
#pragma unroll
    for (int reg = 0; reg < 4; ++reg) {
      const int t = tT + wm * 128 + im * 16 + quad * 4 + reg;
      const float4* xr = (const float4*)(xd + t * 16);
      float4 x0 = xr[0], x1 = xr[1], x2 = xr[2], x3 = xr[3];
#pragma unroll
      for (int jn = 0; jn < 4; ++jn) {
        const int o = oT + wn * 64 + jn * 16 + m16;
        const float4* ur = (const float4*)(up + (size_t)o * R_DIM);
        float lv = dot4(x0, ur[0]) + dot4(x1, ur[1]) +
                   dot4(x2, ur[2]) + dot4(x3, ur[3]);
        y[(size_t)t * O_DIM + o] = acc[im][jn][reg] + lv + bias[o];
      }
    }
  }
}

extern "C" void kernel_launch(void* const* d_in, const int* in_sizes, int n_in,
                              void* d_out, int out_size, void* d_ws, size_t ws_size,
                              hipStream_t stream) {
  const float* x      = (const float*)d_in[0];
  const int*   q      = (const int*)d_in[1];
  const float* scales = (const float*)d_in[2];
  const float* up     = (const float*)d_in[3];
  const float* down   = (const float*)d_in[4];
  const float* alpha  = (const float*)d_in[5];
  const float* bias   = (const float*)d_in[6];
  float* y = (float*)d_out;

  // ws layout: xb bf16 [T,I] (16 MB) | wb bf16 [O,I] (32 MB) | xd f32 [T,16]
  ushort_t* xb = (ushort_t*)d_ws;
  ushort_t* wb = (ushort_t*)((char*)d_ws + (size_t)T_DIM * I_DIM * 2);
  float*    xd = (float*)((char*)d_ws + (size_t)T_DIM * I_DIM * 2 + (size_t)O_DIM * I_DIM * 2);

  hipLaunchKernelGGL(k_xd, dim3(256), dim3(256), 0, stream, x, down, alpha, xd);
  hipLaunchKernelGGL(k_stream, dim3(1536), dim3(256), 0, stream,
                     x, q, scales, xb, wb);
  hipLaunchKernelGGL(k_gemm, dim3(O_DIM / 256, T_DIM / 256), dim3(512), 0, stream,
                     xb, wb, bias, xd, up, y);
}

// Round 10
// 455.691 us; speedup vs baseline: 1.5506x; 1.5506x over previous
//
#include <hip/hip_runtime.h>
#include <hip/hip_bf16.h>
#include <stdint.h>

// Problem dims (fixed by setup_inputs)
#define T_DIM 2048
#define I_DIM 4096
#define O_DIM 4096
#define R_DIM 16
#define QBLK  32

typedef __bf16 bf16x8 __attribute__((ext_vector_type(8)));
typedef float  floatx4 __attribute__((ext_vector_type(4)));
typedef unsigned short ushort_t;

#define AS1 __attribute__((address_space(1)))
#define AS3 __attribute__((address_space(3)))

__device__ __forceinline__ ushort_t f2bf(float f) {
  unsigned u = __float_as_uint(f);
  u += 0x7FFFu + ((u >> 16) & 1u);   // round-to-nearest-even
  return (ushort_t)(u >> 16);
}

__device__ __forceinline__ float dot4(float4 a, float4 b) {
  return a.x * b.x + a.y * b.y + a.z * b.z + a.w * b.w;
}

// ---------------- k_stream (R13): xb=bf16(x) | wb=dequant(q) -----------
__global__ __launch_bounds__(256) void k_stream(const float* __restrict__ x,
                                                const int* __restrict__ q,
                                                const float* __restrict__ scales,
                                                ushort_t* __restrict__ xb,
                                                ushort_t* __restrict__ wb) {
  const int b = blockIdx.x, tid = threadIdx.x;
  if (b < 512) {                              // ---- prep_x
    const int stride = 512 * 256;
    const int u0 = b * 256 + tid;
    float4 v[4][4];
#pragma unroll
    for (int j = 0; j < 4; ++j) {
      const float4* p = (const float4*)x + (size_t)(u0 + j * stride) * 4;
      v[j][0] = p[0]; v[j][1] = p[1]; v[j][2] = p[2]; v[j][3] = p[3];
    }
#pragma unroll
    for (int j = 0; j < 4; ++j) {
      const size_t u = u0 + (size_t)j * stride;
      union { ushort_t us[16]; uint4 o[2]; } r;
#pragma unroll
      for (int k = 0; k < 4; ++k) {
        r.us[k * 4 + 0] = f2bf(v[j][k].x); r.us[k * 4 + 1] = f2bf(v[j][k].y);
        r.us[k * 4 + 2] = f2bf(v[j][k].z); r.us[k * 4 + 3] = f2bf(v[j][k].w);
      }
      ((uint4*)xb)[u * 2] = r.o[0];
      ((uint4*)xb)[u * 2 + 1] = r.o[1];
    }
    return;
  }
  {                                           // ---- prep_w
    const int stride = 1024 * 256;
    const int u0 = (b - 512) * 256 + tid;
    int4 v[4][4];
    float s[4];
#pragma unroll
    for (int j = 0; j < 4; ++j) {
      const size_t u = u0 + (size_t)j * stride;
      const int4* p = (const int4*)q + u * 4;
      v[j][0] = p[0]; v[j][1] = p[1]; v[j][2] = p[2]; v[j][3] = p[3];
      const size_t e = u * 16;
      s[j] = scales[(e >> 12) * (I_DIM / QBLK) + ((e & 4095) >> 5)];
    }
#pragma unroll
    for (int j = 0; j < 4; ++j) {
      const size_t u = u0 + (size_t)j * stride;
      const float sj = s[j];
      union { ushort_t us[16]; uint4 o[2]; } r;
#pragma unroll
      for (int k = 0; k < 4; ++k) {
        r.us[k * 4 + 0] = f2bf((float)(v[j][k].x - 8) * sj);
        r.us[k * 4 + 1] = f2bf((float)(v[j][k].y - 8) * sj);
        r.us[k * 4 + 2] = f2bf((float)(v[j][k].z - 8) * sj);
        r.us[k * 4 + 3] = f2bf((float)(v[j][k].w - 8) * sj);
      }
      ((uint4*)wb)[u * 2] = r.o[0];
      ((uint4*)wb)[u * 2 + 1] = r.o[1];
    }
  }
}

// ---------------- k_xd: xd = alpha * (x @ down^T) ----------------------
__global__ __launch_bounds__(256) void k_xd(const float* __restrict__ x,
                                            const float* __restrict__ down,
                                            const float* __restrict__ alphap,
                                            float* __restrict__ xd) {
  __shared__ float ds[16 * 512];              // 32 KB
  const int b = blockIdx.x, tid = threadIdx.x;
  const int tl = tid >> 5, s = tid & 31;
  const int t = b * 8 + tl;
  float acc[16];
#pragma unroll
  for (int r = 0; r < 16; ++r) acc[r] = 0.f;
  for (int c = 0; c < 8; ++c) {
    const int ib = c * 512;
    __syncthreads();
#pragma unroll
    for (int j = 0; j < 8; ++j) {
      int e = j * 256 + tid;
      int r = e >> 7, col = e & 127;
      ((float4*)ds)[e] = ((const float4*)(down + (size_t)r * I_DIM + ib))[col];
    }
    __syncthreads();
#pragma unroll
    for (int j = 0; j < 4; ++j) {
      float4 xv = ((const float4*)(x + (size_t)t * I_DIM + ib))[s + 32 * j];
#pragma unroll
      for (int r = 0; r < 16; ++r) {
        float4 dv = ((const float4*)ds)[r * 128 + s + 32 * j];
        acc[r] += dot4(xv, dv);
      }
    }
  }
  const float al = alphap[0];
#pragma unroll
  for (int r = 0; r < 16; ++r) {
    float v = acc[r];
    v += __shfl_down(v, 16, 32);
    v += __shfl_down(v, 8, 32);
    v += __shfl_down(v, 4, 32);
    v += __shfl_down(v, 2, 32);
    v += __shfl_down(v, 1, 32);
    if (s == 0) xd[t * 16 + r] = v * al;
  }
}

// ======================= R15 main GEMM =================================
// R14's decisive null: 0.5 blocks/CU doubled time at constant per-block
// delivery -> law: time = per-CU staged bytes / per-CU delivery, with
// per-BLOCK delivery capped ~2-5 B/cy (counted-vmcnt ring: 4.6; drain:
// 2-3) and per-CU = sum over resident blocks. m97's 874 TF = 5.3 B/cy
// x 4 blocks/CU; m102's N=2048 cliff (320 TF) is the 1-block/CU point
// we kept reproducing. R15 = R9's counted-vmcnt ring schedule (best
// per-block, 4.6) shrunk to 4 resident blocks/CU:
//  - Tile 128(T) x 64(O), BK=32 -> grid 64x16 = 1024 blocks = 4/CU.
//  - 256 thr / 4 waves (2Mx2N), per-wave 64x32, acc[4][2] = 32 AGPR;
//    __launch_bounds__(256,4) caps regs <=128 -> 16 waves/CU.
//  - Ring-3 LDS: 3 x (8KB A + 4KB B) = 36 KB -> 4 blocks/CU (144 KB).
//  - Per tile: 3 gload_lds/thread (A:2, B:1), 6 ds_read_b128 + 8 MFMA
//    per wave, ONE barrier, steady vmcnt(3) (2 tiles in flight).
//  - 4-slot granule swizzle cg = (seg&3)^(r&3) on both stage-src and
//    read (involution); wave reads each 16-row stripe's full granule
//    grid exactly once -> uniform bank coverage.

#define BK 32
#define NT (I_DIM / BK)        // 128 K-tiles
#define A_E (128 * BK)         // 4096 elems = 8 KB per A slot
#define B_E (64 * BK)          // 2048 elems = 4 KB per B slot

__device__ __forceinline__ bf16x8 lds_read16(unsigned addr) {
  bf16x8 d;
  asm volatile("ds_read_b128 %0, %1" : "=v"(d) : "v"(addr));
  return d;
}

__device__ __forceinline__ void stage3(const ushort_t* __restrict__ ga,
                                       const ushort_t* __restrict__ gb,
                                       ushort_t* Ast, ushort_t* Bst, int tid) {
  // A: 128x32 bf16 = 512 granules -> 2/thread; B: 64x32 = 256 -> 1/thread.
  // LDS dest linear; global col-granule pre-swizzled (seg&3)^(r&3).
#pragma unroll
  for (int it = 0; it < 2; ++it) {
    const int seg = it * 256 + tid;
    const int r = seg >> 2, cg = (seg & 3) ^ (r & 3);
    __builtin_amdgcn_global_load_lds(
        (const AS1 char*)(ga + (size_t)r * I_DIM + cg * 8),
        (AS3 char*)(Ast + (size_t)seg * 8), 16, 0, 0);
  }
  {
    const int seg = tid;
    const int r = seg >> 2, cg = (seg & 3) ^ (r & 3);
    __builtin_amdgcn_global_load_lds(
        (const AS1 char*)(gb + (size_t)r * I_DIM + cg * 8),
        (AS3 char*)(Bst + (size_t)seg * 8), 16, 0, 0);
  }
}

// One K-tile. VM: vmcnt at tile end (3 steady / 0 / -1 none). STG: stage kt+2.
template<int VM, bool STG>
__device__ __forceinline__ void ktile(unsigned aB, unsigned bB,
                                      ushort_t* Ast, ushort_t* Bst,
                                      const ushort_t* ga, const ushort_t* gb,
                                      floatx4 (&acc)[4][2], int tid) {
  const int lane = tid & 63, wv = tid >> 6;
  const int quad = lane >> 4, m16 = lane & 15;
  const int wm = wv >> 1, wn = wv & 1;

  if constexpr (STG) stage3(ga, gb, Ast, Bst, tid);

  bf16x8 af[4], bf[2];
#pragma unroll
  for (int i = 0; i < 4; ++i) {
    const int m = wm * 64 + i * 16 + m16;
    af[i] = lds_read16(aB + (unsigned)((m * 4 + (quad ^ (m & 3))) * 16));
  }
#pragma unroll
  for (int j = 0; j < 2; ++j) {
    const int n = wn * 32 + j * 16 + m16;
    bf[j] = lds_read16(bB + (unsigned)((n * 4 + (quad ^ (n & 3))) * 16));
  }
  asm volatile("s_waitcnt lgkmcnt(0)" ::: "memory");
  __builtin_amdgcn_sched_barrier(0);
  __builtin_amdgcn_s_setprio(1);
#pragma unroll
  for (int i = 0; i < 4; ++i)
#pragma unroll
    for (int j = 0; j < 2; ++j)
      acc[i][j] = __builtin_amdgcn_mfma_f32_16x16x32_bf16(af[i], bf[j], acc[i][j], 0, 0, 0);
  __builtin_amdgcn_s_setprio(0);
  if constexpr (VM == 3)      asm volatile("s_waitcnt vmcnt(3)" ::: "memory");
  else if constexpr (VM == 0) asm volatile("s_waitcnt vmcnt(0)" ::: "memory");
  if constexpr (VM >= 0) __builtin_amdgcn_sched_barrier(0);
  __builtin_amdgcn_s_barrier();
}

__global__ __launch_bounds__(256, 4) void k_gemm(const ushort_t* __restrict__ xb,
                                                 const ushort_t* __restrict__ wb,
                                                 const float* __restrict__ bias,
                                                 const float* __restrict__ xd,
                                                 const float* __restrict__ up,
                                                 float* __restrict__ y) {
  __shared__ __align__(16) ushort_t As[3][A_E];   // 24 KB
  __shared__ __align__(16) ushort_t Bs[3][B_E];   // 12 KB

  const int tid = threadIdx.x;
  const int oT = blockIdx.x * 64, tT = blockIdx.y * 128;
  const ushort_t* ap = xb + (size_t)tT * I_DIM;
  const ushort_t* bp = wb + (size_t)oT * I_DIM;

  const unsigned aL = (unsigned)(uintptr_t)(AS3 ushort_t*)&As[0][0];
  const unsigned bL = (unsigned)(uintptr_t)(AS3 ushort_t*)&Bs[0][0];
  const unsigned aS0 = aL, aS1 = aL + A_E * 2, aS2 = aL + A_E * 4;
  const unsigned bS0 = bL, bS1 = bL + B_E * 2, bS2 = bL + B_E * 4;

  floatx4 acc[4][2] = {};

  // Prologue: stage tiles 0,1 (6 loads/thread); vmcnt(3) -> tile0 ready.
  stage3(ap, bp, As[0], Bs[0], tid);
  stage3(ap + BK, bp + BK, As[1], Bs[1], tid);
  asm volatile("s_waitcnt vmcnt(3)" ::: "memory");
  __builtin_amdgcn_sched_barrier(0);
  __builtin_amdgcn_s_barrier();

  // Main loop: kt = 0..125 in slot-triples; stage kt+2 -> slot (kt+2)%3.
  int kc = 2 * BK;
  for (int g = 0; g < 42; ++g) {
    ktile<3, true>(aS0, bS0, As[2], Bs[2], ap + kc, bp + kc, acc, tid); kc += BK;
    ktile<3, true>(aS1, bS1, As[0], Bs[0], ap + kc, bp + kc, acc, tid); kc += BK;
    ktile<3, true>(aS2, bS2, As[1], Bs[1], ap + kc, bp + kc, acc, tid); kc += BK;
  }
  // kt=126 (slot0): drain tile127; kt=127 (slot1): compute only.
  ktile<0, false>(aS0, bS0, nullptr, nullptr, nullptr, nullptr, acc, tid);
  ktile<-1, false>(aS1, bS1, nullptr, nullptr, nullptr, nullptr, acc, tid);

  // Epilogue: y[t][o] = acc + dot16(xd[t], up[o]) + bias[o]
  // C/D layout: row = quad*4+reg, col = lane&15 (m89-verified).
  const int lane = tid & 63, wv = tid >> 6;
  const int quad = lane >> 4, m16 = lane & 15;
  const int wm = wv >> 1, wn = wv & 1;
#pragma unroll
  for (int im = 0; im < 4; ++im) {
#pragma unroll
    for (int reg = 0; reg < 4; ++reg) {
      const int t = tT + wm * 64 + im * 16 + quad * 4 + reg;
      const float4* xr = (const float4*)(xd + t * 16);
      float4 x0 = xr[0], x1 = xr[1], x2 = xr[2], x3 = xr[3];
#pragma unroll
      for (int jn = 0; jn < 2; ++jn) {
        const int o = oT + wn * 32 + jn * 16 + m16;
        const float4* ur = (const float4*)(up + (size_t)o * R_DIM);
        float lv = dot4(x0, ur[0]) + dot4(x1, ur[1]) +
                   dot4(x2, ur[2]) + dot4(x3, ur[3]);
        y[(size_t)t * O_DIM + o] = acc[im][jn][reg] + lv + bias[o];
      }
    }
  }
}

extern "C" void kernel_launch(void* const* d_in, const int* in_sizes, int n_in,
                              void* d_out, int out_size, void* d_ws, size_t ws_size,
                              hipStream_t stream) {
  const float* x      = (const float*)d_in[0];
  const int*   q      = (const int*)d_in[1];
  const float* scales = (const float*)d_in[2];
  const float* up     = (const float*)d_in[3];
  const float* down   = (const float*)d_in[4];
  const float* alpha  = (const float*)d_in[5];
  const float* bias   = (const float*)d_in[6];
  float* y = (float*)d_out;

  // ws layout: xb bf16 [T,I] (16 MB) | wb bf16 [O,I] (32 MB) | xd f32 [T,16]
  ushort_t* xb = (ushort_t*)d_ws;
  ushort_t* wb = (ushort_t*)((char*)d_ws + (size_t)T_DIM * I_DIM * 2);
  float*    xd = (float*)((char*)d_ws + (size_t)T_DIM * I_DIM * 2 + (size_t)O_DIM * I_DIM * 2);

  hipLaunchKernelGGL(k_xd, dim3(256), dim3(256), 0, stream, x, down, alpha, xd);
  hipLaunchKernelGGL(k_stream, dim3(1536), dim3(256), 0, stream,
                     x, q, scales, xb, wb);
  hipLaunchKernelGGL(k_gemm, dim3(O_DIM / 64, T_DIM / 128), dim3(256), 0, stream,
                     xb, wb, bias, xd, up, y);
}